// Round 10
// baseline (306.682 us; speedup 1.0000x reference)
//
#include <hip/hip_runtime.h>
#include <hip/hip_bf16.h>
#include <hip/hip_fp16.h>

// ---------------------------------------------------------------------------
// GCN link predictor, fp16 intermediates + MFMA GEMMs (fp32 accumulate):
//   h1 = X @ W1                                  (MFMA GEMM, fp32 A, UNSCALED)
//   z1 = relu(dinv[v]*(dinv[v]*h1[v] + sum dinv[s]*h1[s]) + b1)   (gather)
//   h2 = z1 @ W2                                 (MFMA GEMM, fp16 A, UNSCALED)
//   z2 = relu(dinv[v]*(dinv[v]*h2[v] + sum dinv[s]*h2[s]) + b2)   (gather)
//   out[e] = dot(z2[s], z2[d])
//
// R22: csr pull rebuilt. R21 profiling EXPOSED k_csr_gemm = 50 us (MfmaUtil
// 2.2%, VALUBusy 7.7% -> csr pull latency-chain is the long pole, gemm part
// ~13 us). Two fixes:
//   (a) BIN_EDGES 2048 -> 16384 (NBIN 782 -> 98): per-bucket runs grow from
//       ~5 edges (21B, partial line) to ~42 (168B, 1-2 full lines); P 1.2MB
//       -> 153KB. Bin kernel now two-pass (histogram; re-read + place) since
//       64 edges/thread no longer fit in regs. Pass-2 dst re-read is L2-warm.
//   (b) wave-cooperative pull: (p0,p1) wave-uniform broadcast; lane0 takes
//       LDS cursor; 64 lanes copy the run coalesced. Replaces thread-serial
//       copies (and R21's divergent 2-way interleave, REVERTED).
// Gathers restored to full dispatch (R21 split cost part of +25 us).
// R21: coop mega abandoned (6.25x slower: runtime restricts concurrency).
// R18: privatized binning (-29.7 us). R17: dinv deferred into gather.
// R16: gather THROUGHPUT-bound on L2-miss path; 62 us floor; occupancy-
// insensitive. R13: row-major 256B rows only. R10-R12: gather unfused.
// ---------------------------------------------------------------------------

typedef _Float16 half8 __attribute__((ext_vector_type(8)));
typedef float floatx4 __attribute__((ext_vector_type(4)));

#define BK_SHIFT 8
#define BIN_EDGES 16384 // edges per bin block (R22: was 2048)
#define SLAB_CAP 5120   // per-bucket capacity (mean 4092, sd 64, +16 sigma)
#define WPAD 136        // padded LDS row stride (halfs)

// ---------------------------------------------------------------------------
// k_bin: two-pass private bucket-sort of 16384 edges/block + wprep tail.
// blocks [0, nbin): binning. blocks [nbin, nbin+256): wprep (128 lanes).
// ---------------------------------------------------------------------------
__global__ __launch_bounds__(256) void k_bin(const int* __restrict__ src,
                                             const int* __restrict__ dst,
                                             int* __restrict__ bins,
                                             int* __restrict__ P,
                                             int E, int nbk, int nbin,
                                             const float* __restrict__ W1,
                                             const float* __restrict__ W2,
                                             _Float16* __restrict__ WT1,
                                             _Float16* __restrict__ WT2) {
    int tid = threadIdx.x;
    if ((int)blockIdx.x >= nbin) {
        // ---- weight prep: transpose + fp16 cast (2 x 128x128) ----
        int b2 = blockIdx.x - nbin;          // 0..255
        if (tid < 128) {
            const float* W = (b2 < 128) ? W1 : W2;
            _Float16* WT = (b2 < 128) ? WT1 : WT2;
            int k = b2 & 127;
            WT[tid * 128 + k] = (_Float16)W[k * 128 + tid];
        }
        return;
    }

    __shared__ int lcnt[1024];       // counts -> fill cursor
    __shared__ int delta[1024];      // bucket base (intra-block offset)
    __shared__ int ssum[256];        // block-scan workspace
    __shared__ int stage[BIN_EDGES]; // 64 KB
    int e0 = blockIdx.x * BIN_EDGES;
    int nloc = E - e0; if (nloc > BIN_EDGES) nloc = BIN_EDGES;

    for (int b = tid; b < nbk; b += 256) lcnt[b] = 0;
    __syncthreads();

    // pass 1: histogram of dst buckets (coalesced read)
    for (int j = tid; j < nloc; j += 256)
        atomicAdd(&lcnt[dst[e0 + j] >> BK_SHIFT], 1);
    __syncthreads();

    const int gpb = (nbk + 255) >> 8;   // 2 for nbk=391
    int c[4], mysum = 0;
    for (int t = 0; t < gpb; ++t) {
        int b = tid * gpb + t;
        c[t] = (b < nbk) ? lcnt[b] : 0;
        mysum += c[t];
    }
    ssum[tid] = mysum;
    __syncthreads();
    for (int off = 1; off < 256; off <<= 1) {
        int t = (tid >= off) ? ssum[tid - off] : 0;
        __syncthreads();
        ssum[tid] += t;
        __syncthreads();
    }
    int base = ssum[tid] - mysum;
    for (int t = 0; t < gpb; ++t) {
        int b = tid * gpb + t;
        if (b < nbk) {
            delta[b] = base;
            lcnt[b] = base;
            base += c[t];
        }
    }
    __syncthreads();

    // pass 2: re-read (dst L2-warm) + place packed edges into LDS stage
    for (int j = tid; j < nloc; j += 256) {
        int d = dst[e0 + j];
        int s = src[e0 + j];
        int lp = atomicAdd(&lcnt[d >> BK_SHIFT], 1);
        stage[lp] = (s << 8) | (d & 255);
    }
    __syncthreads();

    // private contiguous writes: fully coalesced, no sharing
    int* bb = bins + (size_t)blockIdx.x * BIN_EDGES;
    for (int j = tid; j < nloc; j += 256) bb[j] = stage[j];
    int prow = nbk + 1;
    int* pp = P + (size_t)blockIdx.x * prow;
    for (int b = tid; b <= nbk; b += 256)
        pp[b] = (b < nbk) ? delta[b] : nloc;
}

// ---------------------------------------------------------------------------
// FUSED: csr-build (blocks 0..nbk-1) || gemm1 (blocks nbk..nbk+gb-1).
// csr path: wave-cooperative pull of bucket b's runs (mean 42 edges, 168B)
// from 98 private segments into LDS, then counting sort -> srcs slab.
// gemm path: unscaled (N x 128)@(128 x 128), 34.8 KB LDS (union'd).
// ---------------------------------------------------------------------------
template <typename AT>
__global__ __launch_bounds__(256) void k_csr_gemm(const int* __restrict__ bins,
                                                  const int* __restrict__ P,
                                                  int* __restrict__ row_start,
                                                  int* __restrict__ cnt,
                                                  float* __restrict__ dinv,
                                                  int* __restrict__ srcs,
                                                  const AT* __restrict__ X,
                                                  const _Float16* __restrict__ WT,
                                                  _Float16* __restrict__ G,
                                                  int n, int nbk, int nbin) {
    __shared__ __align__(16) char smem[128 * WPAD * 2];   // 34816 B union
    int tid = threadIdx.x;

    if ((int)blockIdx.x < nbk) {
        // ---------------- CSR path ----------------
        int* stage = (int*)smem;                    // [SLAB_CAP] 20480 B
        int* lcnt  = (int*)(smem + 20480);          // [256]
        int* lpos  = (int*)(smem + 21504);          // [256]
        int* curs  = (int*)(smem + 22528);          // [1]
        int b = blockIdx.x;
        int prow = nbk + 1;
        if (tid == 0) *curs = 0;
        __syncthreads();
        // phase A: wave-cooperative pull. (p0,p1) are wave-uniform; lane 0
        // claims LDS cursor; 64 lanes copy the run coalesced (R22).
        int wave = tid >> 6, lane = tid & 63;
        for (int seg = wave; seg < nbin; seg += 4) {
            const int* pp = P + (size_t)seg * prow + b;
            int p0 = pp[0], p1 = pp[1];
            int len = p1 - p0;
            if (len > 0) {
                int off = 0;
                if (lane == 0) off = atomicAdd(curs, len);
                off = __shfl(off, 0, 64);
                const int* sp = bins + (size_t)seg * BIN_EDGES + p0;
                for (int i = lane; i < len; i += 64)
                    stage[off + i] = sp[i];
            }
        }
        __syncthreads();
        int tot = *curs;
        // phase B: counting sort over 256 dst slots
        lcnt[tid] = 0;
        __syncthreads();
        for (int i = tid; i < tot; i += 256)
            atomicAdd(&lcnt[stage[i] & 255], 1);
        __syncthreads();
        int c = lcnt[tid];
        lpos[tid] = c;
        __syncthreads();
        for (int off = 1; off < 256; off <<= 1) {
            int t = (tid >= off) ? lpos[tid - off] : 0;
            __syncthreads();
            lpos[tid] += t;
            __syncthreads();
        }
        int rs = b * SLAB_CAP + lpos[tid] - c;   // row start in srcs slab
        int v = (b << BK_SHIFT) + tid;
        if (v < n) {
            row_start[v] = rs;
            cnt[v] = c;
            dinv[v] = rsqrtf((float)c + 1.0f);
        }
        __syncthreads();
        lpos[tid] = rs;                 // reuse as fill cursor
        __syncthreads();
        for (int i = tid; i < tot; i += 256) {
            int p = stage[i];
            int loc = atomicAdd(&lpos[p & 255], 1);
            srcs[loc] = p >> 8;
        }
        return;
    }

    // ---------------- GEMM path (unscaled epilogue) ----------------
    _Float16* Wl = (_Float16*)smem;    // [128 * WPAD]
    {
        const half8* w8 = (const half8*)WT;
#pragma unroll
        for (int i = 0; i < 8; ++i) {
            int idx = i * 256 + tid;
            int r = idx >> 4, cc = idx & 15;
            *(half8*)(Wl + r * WPAD + cc * 8) = w8[idx];
        }
    }
    __syncthreads();

    auto loadA = [](const AT* p) -> half8 {
        if constexpr (sizeof(AT) == 4) {
            const float4* f = (const float4*)p;
            float4 f0 = f[0], f1 = f[1];
            half8 a;
            a[0] = (_Float16)f0.x; a[1] = (_Float16)f0.y;
            a[2] = (_Float16)f0.z; a[3] = (_Float16)f0.w;
            a[4] = (_Float16)f1.x; a[5] = (_Float16)f1.y;
            a[6] = (_Float16)f1.z; a[7] = (_Float16)f1.w;
            return a;
        } else {
            return *(const half8*)p;
        }
    };

    int bid = blockIdx.x - nbk;
    int wave = tid >> 6, lane = tid & 63;
    int q = lane >> 4, ln = lane & 15;
    int m0 = bid * 128 + wave * 32;
    int mA0 = m0 + ln;      if (mA0 >= n) mA0 = n - 1;
    int mA1 = m0 + 16 + ln; if (mA1 >= n) mA1 = n - 1;
    const AT* xr0 = X + (size_t)mA0 * 128;
    const AT* xr1 = X + (size_t)mA1 * 128;

    floatx4 acc[2][8];
#pragma unroll
    for (int p = 0; p < 2; ++p)
#pragma unroll
        for (int t = 0; t < 8; ++t) acc[p][t] = (floatx4){0.f, 0.f, 0.f, 0.f};

#pragma unroll
    for (int kc = 0; kc < 128; kc += 32) {
        half8 a0 = loadA(xr0 + kc + q * 8);
        half8 a1 = loadA(xr1 + kc + q * 8);
#pragma unroll
        for (int t = 0; t < 8; ++t) {
            half8 b = *(const half8*)(Wl + (size_t)(t * 16 + ln) * WPAD + kc + q * 8);
            acc[0][t] = __builtin_amdgcn_mfma_f32_16x16x32_f16(a0, b, acc[0][t], 0, 0, 0);
            acc[1][t] = __builtin_amdgcn_mfma_f32_16x16x32_f16(a1, b, acc[1][t], 0, 0, 0);
        }
    }

#pragma unroll
    for (int p = 0; p < 2; ++p) {
#pragma unroll
        for (int r = 0; r < 4; ++r) {
            int row = m0 + p * 16 + q * 4 + r;
            if (row < n) {
                _Float16* grow = G + (size_t)row * 128 + ln;
#pragma unroll
                for (int t = 0; t < 8; ++t)
                    grow[t * 16] = (_Float16)acc[p][t][r];
            }
        }
    }
}

// ---------------------------------------------------------------------------
// Standalone unscaled GEMM (layer 2).
// ---------------------------------------------------------------------------
template <typename AT>
__global__ __launch_bounds__(256) void k_gemm_mfma(const AT* __restrict__ X,
                                                   const _Float16* __restrict__ WT,
                                                   _Float16* __restrict__ G, int n) {
    __shared__ _Float16 Wl[128 * WPAD];
    int tid = threadIdx.x;
    {
        const half8* w8 = (const half8*)WT;
#pragma unroll
        for (int i = 0; i < 8; ++i) {
            int idx = i * 256 + tid;
            int r = idx >> 4, cc = idx & 15;
            *(half8*)(Wl + r * WPAD + cc * 8) = w8[idx];
        }
    }
    __syncthreads();

    auto loadA = [](const AT* p) -> half8 {
        if constexpr (sizeof(AT) == 4) {
            const float4* f = (const float4*)p;
            float4 f0 = f[0], f1 = f[1];
            half8 a;
            a[0] = (_Float16)f0.x; a[1] = (_Float16)f0.y;
            a[2] = (_Float16)f0.z; a[3] = (_Float16)f0.w;
            a[4] = (_Float16)f1.x; a[5] = (_Float16)f1.y;
            a[6] = (_Float16)f1.z; a[7] = (_Float16)f1.w;
            return a;
        } else {
            return *(const half8*)p;
        }
    };

    int wave = tid >> 6, lane = tid & 63;
    int q = lane >> 4, ln = lane & 15;
    int m0 = blockIdx.x * 128 + wave * 32;
    int mA0 = m0 + ln;      if (mA0 >= n) mA0 = n - 1;
    int mA1 = m0 + 16 + ln; if (mA1 >= n) mA1 = n - 1;
    const AT* xr0 = X + (size_t)mA0 * 128;
    const AT* xr1 = X + (size_t)mA1 * 128;

    floatx4 acc[2][8];
#pragma unroll
    for (int p = 0; p < 2; ++p)
#pragma unroll
        for (int t = 0; t < 8; ++t) acc[p][t] = (floatx4){0.f, 0.f, 0.f, 0.f};

#pragma unroll
    for (int kc = 0; kc < 128; kc += 32) {
        half8 a0 = loadA(xr0 + kc + q * 8);
        half8 a1 = loadA(xr1 + kc + q * 8);
#pragma unroll
        for (int t = 0; t < 8; ++t) {
            half8 b = *(const half8*)(Wl + (size_t)(t * 16 + ln) * WPAD + kc + q * 8);
            acc[0][t] = __builtin_amdgcn_mfma_f32_16x16x32_f16(a0, b, acc[0][t], 0, 0, 0);
            acc[1][t] = __builtin_amdgcn_mfma_f32_16x16x32_f16(a1, b, acc[1][t], 0, 0, 0);
        }
    }

#pragma unroll
    for (int p = 0; p < 2; ++p) {
#pragma unroll
        for (int r = 0; r < 4; ++r) {
            int row = m0 + p * 16 + q * 4 + r;
            if (row < n) {
                _Float16* grow = G + (size_t)row * 128 + ln;
#pragma unroll
                for (int t = 0; t < 8; ++t)
                    grow[t * 16] = (_Float16)acc[p][t][r];
            }
        }
    }
}

// ---------------------------------------------------------------------------
// Gather + bias + relu -> Z (fp16). 16 lanes/node, half8 rows, fp32 accum.
// Per-edge dinv[s] scaling (deferred from gemm). 4-deep unroll (R0 proven;
// R16: deeper unroll neutral — miss-path throughput bound). Full dispatch
// restored (R21 split reverted).
// ---------------------------------------------------------------------------
__global__ __launch_bounds__(256) void k_gather_relu(const _Float16* __restrict__ G,
                                                     const int* __restrict__ srcs,
                                                     const int* __restrict__ row_start,
                                                     const int* __restrict__ cnt,
                                                     const float* __restrict__ dinv,
                                                     const float* __restrict__ bias,
                                                     _Float16* __restrict__ Z, int n) {
    int v = blockIdx.x * 16 + (threadIdx.x >> 4);
    int lane = threadIdx.x & 15;
    if (v >= n) return;
    const half8* G8 = (const half8*)G;

    float dv = dinv[v];
    half8 self = G8[(size_t)v * 16 + lane];
    float acc[8], acc2[8];
#pragma unroll
    for (int j = 0; j < 8; ++j) { acc[j] = dv * (float)self[j]; acc2[j] = 0.f; }

    int beg = row_start[v], deg = cnt[v];
    int e = 0;
    for (; e + 3 < deg; e += 4) {
        int s0 = srcs[beg + e];
        int s1 = srcs[beg + e + 1];
        int s2 = srcs[beg + e + 2];
        int s3 = srcs[beg + e + 3];
        float d0 = dinv[s0];
        float d1 = dinv[s1];
        float d2 = dinv[s2];
        float d3 = dinv[s3];
        half8 t0 = G8[(size_t)s0 * 16 + lane];
        half8 t1 = G8[(size_t)s1 * 16 + lane];
        half8 t2 = G8[(size_t)s2 * 16 + lane];
        half8 t3 = G8[(size_t)s3 * 16 + lane];
#pragma unroll
        for (int j = 0; j < 8; ++j) {
            acc[j]  += d0 * (float)t0[j] + d1 * (float)t1[j];
            acc2[j] += d2 * (float)t2[j] + d3 * (float)t3[j];
        }
    }
    for (; e < deg; ++e) {
        int s0 = srcs[beg + e];
        float d0 = dinv[s0];
        half8 t0 = G8[(size_t)s0 * 16 + lane];
#pragma unroll
        for (int j = 0; j < 8; ++j) acc[j] += d0 * (float)t0[j];
    }

    const float4* b4 = (const float4*)bias;
    float4 bb0 = b4[lane * 2], bb1 = b4[lane * 2 + 1];
    float bf[8] = {bb0.x, bb0.y, bb0.z, bb0.w, bb1.x, bb1.y, bb1.z, bb1.w};
    half8 zo;
#pragma unroll
    for (int j = 0; j < 8; ++j) {
        float z = dv * (acc[j] + acc2[j]) + bf[j];
        zo[j] = (_Float16)fmaxf(z, 0.f);
    }
    ((half8*)Z)[(size_t)v * 16 + lane] = zo;
}

// ---------------------------------------------------------------------------
// Decode: out[e] = dot(Z[s_e], Z[d_e]) over 128 dims (fp16 rows, fp32 accum).
// ---------------------------------------------------------------------------
__global__ __launch_bounds__(256) void k_decode(const _Float16* __restrict__ Z,
                                                const int* __restrict__ eli,
                                                float* __restrict__ out, int el) {
    int sub = threadIdx.x >> 4, lane = threadIdx.x & 15;
    int e = blockIdx.x * 16 + sub;
    if (e >= el) return;
    int s = eli[e], d = eli[el + e];
    const half8* Z8 = (const half8*)Z;
    half8 a = Z8[(size_t)s * 16 + lane];
    half8 b = Z8[(size_t)d * 16 + lane];
    float dot = 0.f;
#pragma unroll
    for (int j = 0; j < 8; ++j) dot += (float)a[j] * (float)b[j];
#pragma unroll
    for (int off = 8; off; off >>= 1) dot += __shfl_down(dot, off, 16);
    if (lane == 0) out[e] = dot;
}

extern "C" void kernel_launch(void* const* d_in, const int* in_sizes, int n_in,
                              void* d_out, int out_size, void* d_ws, size_t ws_size,
                              hipStream_t stream) {
    const float* x  = (const float*)d_in[0];
    const int*  ei  = (const int*)d_in[1];
    const int*  eli = (const int*)d_in[2];
    const float* W1 = (const float*)d_in[3];
    const float* b1 = (const float*)d_in[4];
    const float* W2 = (const float*)d_in[5];
    const float* b2 = (const float*)d_in[6];
    float* out = (float*)d_out;

    const int N  = in_sizes[0] / 128;
    const int E  = in_sizes[1] / 2;
    const int EL = in_sizes[2] / 2;
    const int* src = ei;
    const int* dst = ei + E;
    const int NBK  = (N + 255) >> BK_SHIFT;                 // 391
    const int NBIN = (E + BIN_EDGES - 1) / BIN_EDGES;       // 98
    const int GB   = (N + 127) / 128;                       // 782

    char* ws = (char*)d_ws;
    size_t off = 0;
    auto alloc = [&](size_t bytes) -> void* {
        void* p = ws + off;
        off += bytes;
        off = (off + 255) & ~(size_t)255;
        return p;
    };
    int*       cnt       = (int*)alloc((size_t)N * 4);
    int*       row_start = (int*)alloc((size_t)N * 4);
    float*     dinv      = (float*)alloc((size_t)N * 4);
    _Float16*  WT1       = (_Float16*)alloc(128 * 128 * 2);
    _Float16*  WT2       = (_Float16*)alloc(128 * 128 * 2);
    int*       srcs      = (int*)alloc((size_t)NBK * SLAB_CAP * 4);
    int*       bins      = (int*)alloc((size_t)NBIN * BIN_EDGES * 4);
    int*       P         = (int*)alloc((size_t)NBIN * (NBK + 1) * 4);
    _Float16*  buf0      = (_Float16*)alloc((size_t)N * 128 * 2);  // h1 -> h2
    _Float16*  buf1      = (_Float16*)alloc((size_t)N * 128 * 2);  // z1 -> z2

    // private binning, two-pass (+ weight prep in tail blocks)
    k_bin<<<NBIN + 256, 256, 0, stream>>>(src, dst, bins, P, E, NBK, NBIN,
                                          W1, W2, WT1, WT2);

    // fused: csr (391 blocks) || gemm1 h1 = x@W1 -> buf0 (782 blocks)
    k_csr_gemm<float><<<NBK + GB, 256, 0, stream>>>(bins, P, row_start, cnt, dinv,
                                                    srcs, x, WT1, buf0, N, NBK, NBIN);

    // z1 = relu(dinv*(dinv*h1[v] + sum dinv[s]*h1[s]) + b1) -> buf1
    k_gather_relu<<<(N + 15) / 16, 256, 0, stream>>>(buf0, srcs, row_start, cnt, dinv, b1, buf1, N);
    // layer 2: h2 = z1@W2 -> buf0 ; z2 -> buf1
    k_gemm_mfma<_Float16><<<GB, 256, 0, stream>>>(buf1, WT2, buf0, N);
    k_gather_relu<<<(N + 15) / 16, 256, 0, stream>>>(buf0, srcs, row_start, cnt, dinv, b2, buf1, N);
    // decode
    k_decode<<<(EL + 15) / 16, 256, 0, stream>>>(buf1, eli, out, EL);
}

// Round 11
// 291.461 us; speedup vs baseline: 1.0522x; 1.0522x over previous
//
#include <hip/hip_runtime.h>
#include <hip/hip_bf16.h>
#include <hip/hip_fp16.h>

// ---------------------------------------------------------------------------
// GCN link predictor, fp16 intermediates + MFMA GEMMs (fp32 accumulate):
//   h1 = X @ W1                                  (MFMA GEMM, fp32 A, UNSCALED)
//   z1 = relu(dinv[v]*(dinv[v]*h1[v] + sum dinv[s]*h1[s]) + b1)   (gather)
//   h2 = z1 @ W2                                 (MFMA GEMM, fp16 A, UNSCALED)
//   z2 = relu(dinv[v]*(dinv[v]*h2[v] + sum dinv[s]*h2[s]) + b2)   (gather)
//   out[e] = dot(z2[s], z2[d])
//
// R23: EXACT R18 restore (277.9 us, reproducibly best; harness variance
// <0.5 us) + gather half-split ONLY (R21-validated vbase/vcnt variant) for
// top-5 visibility: halves ~31 us, so any kernel >31 us must surface.
// R21(+25)/R22(+29) lesson: BOTH deviations from R18's bin/csr regressed;
// traffic models for bin/csr repeatedly fail to close (R22 missed by +57) —
// measure in the GOOD config before editing again.
// R19/R20: cooperative mega-kernel abandoned (6.25x slower on this stack;
// fences fixed correctness per G16 but runtime restricts coop concurrency).
// R18: privatized binning: bin writes private coalesced packed segments +
// per-block bucket offsets; csr pulls + LDS counting-sorts. -29.7 vs R17.
// R17: dinv deferred into gather; csr || gemm1 fused (kept).
// R16: gather THROUGHPUT-bound on L2-miss/L3 path (~3.6 TB/s service);
// more MLP = 0 gain; 62 us/gather structural floor; occupancy-insensitive.
// R13: row-major 256B rows only. R10-R12: keep gather unfused from gemm.
// ---------------------------------------------------------------------------

typedef _Float16 half8 __attribute__((ext_vector_type(8)));
typedef float floatx4 __attribute__((ext_vector_type(4)));

#define BK_SHIFT 8
#define BSC_EDGES 2048  // edges per bin block
#define SLAB_CAP 5120   // per-bucket capacity (mean 4092, sd 64, +16 sigma)
#define WPAD 136        // padded LDS row stride (halfs)

// ---------------------------------------------------------------------------
// k_bin: private bucket-sort of 2048 edges/block + weight-prep tail blocks.
// blocks [0, nbin): binning. blocks [nbin, nbin+256): wprep (128 lanes).
// ---------------------------------------------------------------------------
__global__ __launch_bounds__(256) void k_bin(const int* __restrict__ src,
                                             const int* __restrict__ dst,
                                             int* __restrict__ bins,
                                             int* __restrict__ P,
                                             int E, int nbk, int nbin,
                                             const float* __restrict__ W1,
                                             const float* __restrict__ W2,
                                             _Float16* __restrict__ WT1,
                                             _Float16* __restrict__ WT2) {
    int tid = threadIdx.x;
    if ((int)blockIdx.x >= nbin) {
        // ---- weight prep: transpose + fp16 cast (2 x 128x128) ----
        int b2 = blockIdx.x - nbin;          // 0..255
        if (tid < 128) {
            const float* W = (b2 < 128) ? W1 : W2;
            _Float16* WT = (b2 < 128) ? WT1 : WT2;
            int k = b2 & 127;
            WT[tid * 128 + k] = (_Float16)W[k * 128 + tid];
        }
        return;
    }

    __shared__ int lcnt[1024];    // counts -> fill cursor
    __shared__ int delta[1024];   // saved bucket base (intra-block offset)
    __shared__ int ssum[256];     // block-scan workspace
    __shared__ int stage[BSC_EDGES];
    int e0 = blockIdx.x * BSC_EDGES;
    int nloc = E - e0; if (nloc > BSC_EDGES) nloc = BSC_EDGES;

    for (int b = tid; b < nbk; b += 256) lcnt[b] = 0;
    __syncthreads();

    int d[BSC_EDGES / 256], s[BSC_EDGES / 256];
#pragma unroll
    for (int k = 0; k < BSC_EDGES / 256; ++k) {
        int e = e0 + k * 256 + tid;
        if (e < E) {
            d[k] = dst[e];
            s[k] = src[e];
            atomicAdd(&lcnt[d[k] >> BK_SHIFT], 1);
        } else d[k] = -1;
    }
    __syncthreads();

    const int gpb = (nbk + 255) >> 8;   // 2 for nbk=391
    int c[4], mysum = 0;
    for (int t = 0; t < gpb; ++t) {
        int b = tid * gpb + t;
        c[t] = (b < nbk) ? lcnt[b] : 0;
        mysum += c[t];
    }
    ssum[tid] = mysum;
    __syncthreads();
    for (int off = 1; off < 256; off <<= 1) {
        int t = (tid >= off) ? ssum[tid - off] : 0;
        __syncthreads();
        ssum[tid] += t;
        __syncthreads();
    }
    int base = ssum[tid] - mysum;
    for (int t = 0; t < gpb; ++t) {
        int b = tid * gpb + t;
        if (b < nbk) {
            delta[b] = base;
            lcnt[b] = base;
            base += c[t];
        }
    }
    __syncthreads();

#pragma unroll
    for (int k = 0; k < BSC_EDGES / 256; ++k) {
        if (d[k] >= 0) {
            int b = d[k] >> BK_SHIFT;
            int lp = atomicAdd(&lcnt[b], 1);
            stage[lp] = (s[k] << 8) | (d[k] & 255);
        }
    }
    __syncthreads();

    // private contiguous writes: fully coalesced, no sharing
    int* bb = bins + (size_t)blockIdx.x * BSC_EDGES;
    for (int j = tid; j < nloc; j += 256) bb[j] = stage[j];
    int prow = nbk + 1;
    int* pp = P + (size_t)blockIdx.x * prow;
    for (int b = tid; b <= nbk; b += 256)
        pp[b] = (b < nbk) ? delta[b] : nloc;
}

// ---------------------------------------------------------------------------
// FUSED: csr-build (blocks 0..nbk-1) || gemm1 (blocks nbk..nbk+gb-1).
// csr path: pull bucket b's edges from nbin private segments into LDS
// (thread-serial, R18-exact), then counting sort -> srcs slab.
// gemm path: unscaled (N x 128)@(128 x 128), 34.8 KB LDS (union'd).
// ---------------------------------------------------------------------------
template <typename AT>
__global__ __launch_bounds__(256) void k_csr_gemm(const int* __restrict__ bins,
                                                  const int* __restrict__ P,
                                                  int* __restrict__ row_start,
                                                  int* __restrict__ cnt,
                                                  float* __restrict__ dinv,
                                                  int* __restrict__ srcs,
                                                  const AT* __restrict__ X,
                                                  const _Float16* __restrict__ WT,
                                                  _Float16* __restrict__ G,
                                                  int n, int nbk, int nbin) {
    __shared__ __align__(16) char smem[128 * WPAD * 2];   // 34816 B union
    int tid = threadIdx.x;

    if ((int)blockIdx.x < nbk) {
        // ---------------- CSR path (R18-exact) ----------------
        int* stage = (int*)smem;                    // [SLAB_CAP] 20480 B
        int* lcnt  = (int*)(smem + 20480);          // [256]
        int* lpos  = (int*)(smem + 21504);          // [256]
        int* curs  = (int*)(smem + 22528);          // [1]
        int b = blockIdx.x;
        int prow = nbk + 1;
        if (tid == 0) *curs = 0;
        __syncthreads();
        // phase A: pull my bucket's edges from private segments into LDS
        for (int seg = tid; seg < nbin; seg += 256) {
            const int* pp = P + (size_t)seg * prow + b;
            int p0 = pp[0], p1 = pp[1];
            int len = p1 - p0;
            if (len > 0) {
                int off = atomicAdd(curs, len);
                const int* sp = bins + (size_t)seg * BSC_EDGES + p0;
                for (int i = 0; i < len; ++i) stage[off + i] = sp[i];
            }
        }
        __syncthreads();
        int tot = *curs;
        // phase B: counting sort over 256 dst slots
        lcnt[tid] = 0;
        __syncthreads();
        for (int i = tid; i < tot; i += 256)
            atomicAdd(&lcnt[stage[i] & 255], 1);
        __syncthreads();
        int c = lcnt[tid];
        lpos[tid] = c;
        __syncthreads();
        for (int off = 1; off < 256; off <<= 1) {
            int t = (tid >= off) ? lpos[tid - off] : 0;
            __syncthreads();
            lpos[tid] += t;
            __syncthreads();
        }
        int rs = b * SLAB_CAP + lpos[tid] - c;   // row start in srcs slab
        int v = (b << BK_SHIFT) + tid;
        if (v < n) {
            row_start[v] = rs;
            cnt[v] = c;
            dinv[v] = rsqrtf((float)c + 1.0f);
        }
        __syncthreads();
        lpos[tid] = rs;                 // reuse as fill cursor
        __syncthreads();
        for (int i = tid; i < tot; i += 256) {
            int p = stage[i];
            int loc = atomicAdd(&lpos[p & 255], 1);
            srcs[loc] = p >> 8;
        }
        return;
    }

    // ---------------- GEMM path (unscaled epilogue) ----------------
    _Float16* Wl = (_Float16*)smem;    // [128 * WPAD]
    {
        const half8* w8 = (const half8*)WT;
#pragma unroll
        for (int i = 0; i < 8; ++i) {
            int idx = i * 256 + tid;
            int r = idx >> 4, cc = idx & 15;
            *(half8*)(Wl + r * WPAD + cc * 8) = w8[idx];
        }
    }
    __syncthreads();

    auto loadA = [](const AT* p) -> half8 {
        if constexpr (sizeof(AT) == 4) {
            const float4* f = (const float4*)p;
            float4 f0 = f[0], f1 = f[1];
            half8 a;
            a[0] = (_Float16)f0.x; a[1] = (_Float16)f0.y;
            a[2] = (_Float16)f0.z; a[3] = (_Float16)f0.w;
            a[4] = (_Float16)f1.x; a[5] = (_Float16)f1.y;
            a[6] = (_Float16)f1.z; a[7] = (_Float16)f1.w;
            return a;
        } else {
            return *(const half8*)p;
        }
    };

    int bid = blockIdx.x - nbk;
    int wave = tid >> 6, lane = tid & 63;
    int q = lane >> 4, ln = lane & 15;
    int m0 = bid * 128 + wave * 32;
    int mA0 = m0 + ln;      if (mA0 >= n) mA0 = n - 1;
    int mA1 = m0 + 16 + ln; if (mA1 >= n) mA1 = n - 1;
    const AT* xr0 = X + (size_t)mA0 * 128;
    const AT* xr1 = X + (size_t)mA1 * 128;

    floatx4 acc[2][8];
#pragma unroll
    for (int p = 0; p < 2; ++p)
#pragma unroll
        for (int t = 0; t < 8; ++t) acc[p][t] = (floatx4){0.f, 0.f, 0.f, 0.f};

#pragma unroll
    for (int kc = 0; kc < 128; kc += 32) {
        half8 a0 = loadA(xr0 + kc + q * 8);
        half8 a1 = loadA(xr1 + kc + q * 8);
#pragma unroll
        for (int t = 0; t < 8; ++t) {
            half8 b = *(const half8*)(Wl + (size_t)(t * 16 + ln) * WPAD + kc + q * 8);
            acc[0][t] = __builtin_amdgcn_mfma_f32_16x16x32_f16(a0, b, acc[0][t], 0, 0, 0);
            acc[1][t] = __builtin_amdgcn_mfma_f32_16x16x32_f16(a1, b, acc[1][t], 0, 0, 0);
        }
    }

#pragma unroll
    for (int p = 0; p < 2; ++p) {
#pragma unroll
        for (int r = 0; r < 4; ++r) {
            int row = m0 + p * 16 + q * 4 + r;
            if (row < n) {
                _Float16* grow = G + (size_t)row * 128 + ln;
#pragma unroll
                for (int t = 0; t < 8; ++t)
                    grow[t * 16] = (_Float16)acc[p][t][r];
            }
        }
    }
}

// ---------------------------------------------------------------------------
// Standalone unscaled GEMM (layer 2).
// ---------------------------------------------------------------------------
template <typename AT>
__global__ __launch_bounds__(256) void k_gemm_mfma(const AT* __restrict__ X,
                                                   const _Float16* __restrict__ WT,
                                                   _Float16* __restrict__ G, int n) {
    __shared__ _Float16 Wl[128 * WPAD];
    int tid = threadIdx.x;
    {
        const half8* w8 = (const half8*)WT;
#pragma unroll
        for (int i = 0; i < 8; ++i) {
            int idx = i * 256 + tid;
            int r = idx >> 4, cc = idx & 15;
            *(half8*)(Wl + r * WPAD + cc * 8) = w8[idx];
        }
    }
    __syncthreads();

    auto loadA = [](const AT* p) -> half8 {
        if constexpr (sizeof(AT) == 4) {
            const float4* f = (const float4*)p;
            float4 f0 = f[0], f1 = f[1];
            half8 a;
            a[0] = (_Float16)f0.x; a[1] = (_Float16)f0.y;
            a[2] = (_Float16)f0.z; a[3] = (_Float16)f0.w;
            a[4] = (_Float16)f1.x; a[5] = (_Float16)f1.y;
            a[6] = (_Float16)f1.z; a[7] = (_Float16)f1.w;
            return a;
        } else {
            return *(const half8*)p;
        }
    };

    int wave = tid >> 6, lane = tid & 63;
    int q = lane >> 4, ln = lane & 15;
    int m0 = blockIdx.x * 128 + wave * 32;
    int mA0 = m0 + ln;      if (mA0 >= n) mA0 = n - 1;
    int mA1 = m0 + 16 + ln; if (mA1 >= n) mA1 = n - 1;
    const AT* xr0 = X + (size_t)mA0 * 128;
    const AT* xr1 = X + (size_t)mA1 * 128;

    floatx4 acc[2][8];
#pragma unroll
    for (int p = 0; p < 2; ++p)
#pragma unroll
        for (int t = 0; t < 8; ++t) acc[p][t] = (floatx4){0.f, 0.f, 0.f, 0.f};

#pragma unroll
    for (int kc = 0; kc < 128; kc += 32) {
        half8 a0 = loadA(xr0 + kc + q * 8);
        half8 a1 = loadA(xr1 + kc + q * 8);
#pragma unroll
        for (int t = 0; t < 8; ++t) {
            half8 b = *(const half8*)(Wl + (size_t)(t * 16 + ln) * WPAD + kc + q * 8);
            acc[0][t] = __builtin_amdgcn_mfma_f32_16x16x32_f16(a0, b, acc[0][t], 0, 0, 0);
            acc[1][t] = __builtin_amdgcn_mfma_f32_16x16x32_f16(a1, b, acc[1][t], 0, 0, 0);
        }
    }

#pragma unroll
    for (int p = 0; p < 2; ++p) {
#pragma unroll
        for (int r = 0; r < 4; ++r) {
            int row = m0 + p * 16 + q * 4 + r;
            if (row < n) {
                _Float16* grow = G + (size_t)row * 128 + ln;
#pragma unroll
                for (int t = 0; t < 8; ++t)
                    grow[t * 16] = (_Float16)acc[p][t][r];
            }
        }
    }
}

// ---------------------------------------------------------------------------
// Gather + bias + relu -> Z (fp16). 16 lanes/node, half8 rows, fp32 accum.
// Per-edge dinv[s] scaling (deferred from gemm). 4-deep unroll (proven).
// R23: [vbase, vbase+vcnt) range so each gather runs as two ~31 us halves
// (top-5 visibility). Inner code identical to R18.
// ---------------------------------------------------------------------------
__global__ __launch_bounds__(256) void k_gather_relu(const _Float16* __restrict__ G,
                                                     const int* __restrict__ srcs,
                                                     const int* __restrict__ row_start,
                                                     const int* __restrict__ cnt,
                                                     const float* __restrict__ dinv,
                                                     const float* __restrict__ bias,
                                                     _Float16* __restrict__ Z,
                                                     int vbase, int vcnt) {
    int v = vbase + blockIdx.x * 16 + (threadIdx.x >> 4);
    int lane = threadIdx.x & 15;
    if (v >= vbase + vcnt) return;
    const half8* G8 = (const half8*)G;

    float dv = dinv[v];
    half8 self = G8[(size_t)v * 16 + lane];
    float acc[8], acc2[8];
#pragma unroll
    for (int j = 0; j < 8; ++j) { acc[j] = dv * (float)self[j]; acc2[j] = 0.f; }

    int beg = row_start[v], deg = cnt[v];
    int e = 0;
    for (; e + 3 < deg; e += 4) {
        int s0 = srcs[beg + e];
        int s1 = srcs[beg + e + 1];
        int s2 = srcs[beg + e + 2];
        int s3 = srcs[beg + e + 3];
        float d0 = dinv[s0];
        float d1 = dinv[s1];
        float d2 = dinv[s2];
        float d3 = dinv[s3];
        half8 t0 = G8[(size_t)s0 * 16 + lane];
        half8 t1 = G8[(size_t)s1 * 16 + lane];
        half8 t2 = G8[(size_t)s2 * 16 + lane];
        half8 t3 = G8[(size_t)s3 * 16 + lane];
#pragma unroll
        for (int j = 0; j < 8; ++j) {
            acc[j]  += d0 * (float)t0[j] + d1 * (float)t1[j];
            acc2[j] += d2 * (float)t2[j] + d3 * (float)t3[j];
        }
    }
    for (; e < deg; ++e) {
        int s0 = srcs[beg + e];
        float d0 = dinv[s0];
        half8 t0 = G8[(size_t)s0 * 16 + lane];
#pragma unroll
        for (int j = 0; j < 8; ++j) acc[j] += d0 * (float)t0[j];
    }

    const float4* b4 = (const float4*)bias;
    float4 bb0 = b4[lane * 2], bb1 = b4[lane * 2 + 1];
    float bf[8] = {bb0.x, bb0.y, bb0.z, bb0.w, bb1.x, bb1.y, bb1.z, bb1.w};
    half8 zo;
#pragma unroll
    for (int j = 0; j < 8; ++j) {
        float z = dv * (acc[j] + acc2[j]) + bf[j];
        zo[j] = (_Float16)fmaxf(z, 0.f);
    }
    ((half8*)Z)[(size_t)v * 16 + lane] = zo;
}

// ---------------------------------------------------------------------------
// Decode: out[e] = dot(Z[s_e], Z[d_e]) over 128 dims (fp16 rows, fp32 accum).
// ---------------------------------------------------------------------------
__global__ __launch_bounds__(256) void k_decode(const _Float16* __restrict__ Z,
                                                const int* __restrict__ eli,
                                                float* __restrict__ out, int el) {
    int sub = threadIdx.x >> 4, lane = threadIdx.x & 15;
    int e = blockIdx.x * 16 + sub;
    if (e >= el) return;
    int s = eli[e], d = eli[el + e];
    const half8* Z8 = (const half8*)Z;
    half8 a = Z8[(size_t)s * 16 + lane];
    half8 b = Z8[(size_t)d * 16 + lane];
    float dot = 0.f;
#pragma unroll
    for (int j = 0; j < 8; ++j) dot += (float)a[j] * (float)b[j];
#pragma unroll
    for (int off = 8; off; off >>= 1) dot += __shfl_down(dot, off, 16);
    if (lane == 0) out[e] = dot;
}

extern "C" void kernel_launch(void* const* d_in, const int* in_sizes, int n_in,
                              void* d_out, int out_size, void* d_ws, size_t ws_size,
                              hipStream_t stream) {
    const float* x  = (const float*)d_in[0];
    const int*  ei  = (const int*)d_in[1];
    const int*  eli = (const int*)d_in[2];
    const float* W1 = (const float*)d_in[3];
    const float* b1 = (const float*)d_in[4];
    const float* W2 = (const float*)d_in[5];
    const float* b2 = (const float*)d_in[6];
    float* out = (float*)d_out;

    const int N  = in_sizes[0] / 128;
    const int E  = in_sizes[1] / 2;
    const int EL = in_sizes[2] / 2;
    const int* src = ei;
    const int* dst = ei + E;
    const int NBK  = (N + 255) >> BK_SHIFT;                 // 391
    const int NBIN = (E + BSC_EDGES - 1) / BSC_EDGES;       // 782
    const int GB   = (N + 127) / 128;                       // 782

    char* ws = (char*)d_ws;
    size_t off = 0;
    auto alloc = [&](size_t bytes) -> void* {
        void* p = ws + off;
        off += bytes;
        off = (off + 255) & ~(size_t)255;
        return p;
    };
    int*       cnt       = (int*)alloc((size_t)N * 4);
    int*       row_start = (int*)alloc((size_t)N * 4);
    float*     dinv      = (float*)alloc((size_t)N * 4);
    _Float16*  WT1       = (_Float16*)alloc(128 * 128 * 2);
    _Float16*  WT2       = (_Float16*)alloc(128 * 128 * 2);
    int*       srcs      = (int*)alloc((size_t)NBK * SLAB_CAP * 4);
    int*       bins      = (int*)alloc((size_t)NBIN * BSC_EDGES * 4);
    int*       P         = (int*)alloc((size_t)NBIN * (NBK + 1) * 4);
    _Float16*  buf0      = (_Float16*)alloc((size_t)N * 128 * 2);  // h1 -> h2
    _Float16*  buf1      = (_Float16*)alloc((size_t)N * 128 * 2);  // z1 -> z2

    // gather halves: [0, NH) and [NH, N), NH multiple of 16
    const int NH = ((N / 2) + 15) & ~15;
    const int G1 = (NH + 15) / 16;
    const int G2 = (N - NH + 15) / 16;

    // private binning (+ weight prep in tail blocks) — R18-exact
    k_bin<<<NBIN + 256, 256, 0, stream>>>(src, dst, bins, P, E, NBK, NBIN,
                                          W1, W2, WT1, WT2);

    // fused: csr (391 blocks) || gemm1 h1 = x@W1 -> buf0 (782 blocks) — R18-exact
    k_csr_gemm<float><<<NBK + GB, 256, 0, stream>>>(bins, P, row_start, cnt, dinv,
                                                    srcs, x, WT1, buf0, N, NBK, NBIN);

    // z1 = relu(dinv*(dinv*h1[v] + sum dinv[s]*h1[s]) + b1) -> buf1 (2 halves)
    k_gather_relu<<<G1, 256, 0, stream>>>(buf0, srcs, row_start, cnt, dinv, b1, buf1, 0, NH);
    k_gather_relu<<<G2, 256, 0, stream>>>(buf0, srcs, row_start, cnt, dinv, b1, buf1, NH, N - NH);
    // layer 2: h2 = z1@W2 -> buf0 ; z2 -> buf1 (2 halves)
    k_gemm_mfma<_Float16><<<GB, 256, 0, stream>>>(buf1, WT2, buf0, N);
    k_gather_relu<<<G1, 256, 0, stream>>>(buf0, srcs, row_start, cnt, dinv, b2, buf1, 0, NH);
    k_gather_relu<<<G2, 256, 0, stream>>>(buf0, srcs, row_start, cnt, dinv, b2, buf1, NH, N - NH);
    // decode
    k_decode<<<(EL + 15) / 16, 256, 0, stream>>>(buf1, eli, out, EL);
}

// Round 12
// 275.044 us; speedup vs baseline: 1.1150x; 1.0597x over previous
//
#include <hip/hip_runtime.h>
#include <hip/hip_bf16.h>
#include <hip/hip_fp16.h>

// ---------------------------------------------------------------------------
// GCN link predictor, fp16 intermediates + MFMA GEMMs (fp32 accumulate):
//   h1 = X @ W1                                  (MFMA GEMM, fp32 A, UNSCALED)
//   z1 = relu(dinv[v]*(dinv[v]*h1[v] + sum dinv[s]*h1[s]) + b1)   (gather)
//   h2 = z1 @ W2                                 (MFMA GEMM, fp16 A, UNSCALED)
//   z2 = relu(dinv[v]*(dinv[v]*h2[v] + sum dinv[s]*h2[s]) + b2)   (gather)
//   out[e] = dot(z2[s], z2[d])
//
// R24: R18-exact + XCD-bijective bucket swizzle in csr path ONLY.
// R23 measurement (R18-exact csr, split gathers): k_csr_gemm = 41 us,
// FETCH 52 MB vs ~10 MB logical = 5x over-fetch at 1.3 TB/s effective.
// Cause: bucket b and b+1 read ADJACENT bytes of every bin segment (runs
// mean 21B, bins bucket-sorted per segment), but consecutive csr blocks
// round-robin onto different XCDs -> over-fetched lines never reused.
// Fix (T1): bucket = chunked bijective swizzle(blockIdx) so 49 consecutive
// buckets share an XCD; neighbor runs (~1KB/segment) then hit that XCD's L2.
// Also learned (R23): harness fillBuffer 256MB = 40 us fixed on timed path.
// Gather split REVERTED (+13.6 us for 4 extra dispatches — visibility paid).
// R21(+25)/R22(+29): both bin/csr restructures regressed — R18 bodies kept
// byte-identical; swizzle is an address remap only.
// R19/R20: cooperative mega abandoned (6.25x slower; coop concurrency
// restricted on this stack; fences per G16 fixed correctness though).
// R18: privatized binning (277.9 us base). R17: dinv deferred into gather.
// R16: gather THROUGHPUT-bound on random-row service (~3.6 TB/s); 62 us
// floor; occupancy/MLP-insensitive. R13: row-major 256B rows only.
// R10-R12: keep gather unfused from gemm.
// ---------------------------------------------------------------------------

typedef _Float16 half8 __attribute__((ext_vector_type(8)));
typedef float floatx4 __attribute__((ext_vector_type(4)));

#define BK_SHIFT 8
#define BSC_EDGES 2048  // edges per bin block
#define SLAB_CAP 5120   // per-bucket capacity (mean 4092, sd 64, +16 sigma)
#define WPAD 136        // padded LDS row stride (halfs)

// ---------------------------------------------------------------------------
// k_bin: private bucket-sort of 2048 edges/block + weight-prep tail blocks.
// blocks [0, nbin): binning. blocks [nbin, nbin+256): wprep (128 lanes).
// (R18-exact)
// ---------------------------------------------------------------------------
__global__ __launch_bounds__(256) void k_bin(const int* __restrict__ src,
                                             const int* __restrict__ dst,
                                             int* __restrict__ bins,
                                             int* __restrict__ P,
                                             int E, int nbk, int nbin,
                                             const float* __restrict__ W1,
                                             const float* __restrict__ W2,
                                             _Float16* __restrict__ WT1,
                                             _Float16* __restrict__ WT2) {
    int tid = threadIdx.x;
    if ((int)blockIdx.x >= nbin) {
        // ---- weight prep: transpose + fp16 cast (2 x 128x128) ----
        int b2 = blockIdx.x - nbin;          // 0..255
        if (tid < 128) {
            const float* W = (b2 < 128) ? W1 : W2;
            _Float16* WT = (b2 < 128) ? WT1 : WT2;
            int k = b2 & 127;
            WT[tid * 128 + k] = (_Float16)W[k * 128 + tid];
        }
        return;
    }

    __shared__ int lcnt[1024];    // counts -> fill cursor
    __shared__ int delta[1024];   // saved bucket base (intra-block offset)
    __shared__ int ssum[256];     // block-scan workspace
    __shared__ int stage[BSC_EDGES];
    int e0 = blockIdx.x * BSC_EDGES;
    int nloc = E - e0; if (nloc > BSC_EDGES) nloc = BSC_EDGES;

    for (int b = tid; b < nbk; b += 256) lcnt[b] = 0;
    __syncthreads();

    int d[BSC_EDGES / 256], s[BSC_EDGES / 256];
#pragma unroll
    for (int k = 0; k < BSC_EDGES / 256; ++k) {
        int e = e0 + k * 256 + tid;
        if (e < E) {
            d[k] = dst[e];
            s[k] = src[e];
            atomicAdd(&lcnt[d[k] >> BK_SHIFT], 1);
        } else d[k] = -1;
    }
    __syncthreads();

    const int gpb = (nbk + 255) >> 8;   // 2 for nbk=391
    int c[4], mysum = 0;
    for (int t = 0; t < gpb; ++t) {
        int b = tid * gpb + t;
        c[t] = (b < nbk) ? lcnt[b] : 0;
        mysum += c[t];
    }
    ssum[tid] = mysum;
    __syncthreads();
    for (int off = 1; off < 256; off <<= 1) {
        int t = (tid >= off) ? ssum[tid - off] : 0;
        __syncthreads();
        ssum[tid] += t;
        __syncthreads();
    }
    int base = ssum[tid] - mysum;
    for (int t = 0; t < gpb; ++t) {
        int b = tid * gpb + t;
        if (b < nbk) {
            delta[b] = base;
            lcnt[b] = base;
            base += c[t];
        }
    }
    __syncthreads();

#pragma unroll
    for (int k = 0; k < BSC_EDGES / 256; ++k) {
        if (d[k] >= 0) {
            int b = d[k] >> BK_SHIFT;
            int lp = atomicAdd(&lcnt[b], 1);
            stage[lp] = (s[k] << 8) | (d[k] & 255);
        }
    }
    __syncthreads();

    // private contiguous writes: fully coalesced, no sharing
    int* bb = bins + (size_t)blockIdx.x * BSC_EDGES;
    for (int j = tid; j < nloc; j += 256) bb[j] = stage[j];
    int prow = nbk + 1;
    int* pp = P + (size_t)blockIdx.x * prow;
    for (int b = tid; b <= nbk; b += 256)
        pp[b] = (b < nbk) ? delta[b] : nloc;
}

// ---------------------------------------------------------------------------
// FUSED: csr-build (blocks 0..nbk-1) || gemm1 (blocks nbk..nbk+gb-1).
// csr path: bucket = XCD-bijective swizzle(blockIdx) (R24) -> 49 consecutive
// buckets share an XCD; adjacent runs of each bin segment hit L2.
// Body otherwise R18-exact.
// gemm path: unscaled (N x 128)@(128 x 128), 34.8 KB LDS (union'd).
// ---------------------------------------------------------------------------
template <typename AT>
__global__ __launch_bounds__(256) void k_csr_gemm(const int* __restrict__ bins,
                                                  const int* __restrict__ P,
                                                  int* __restrict__ row_start,
                                                  int* __restrict__ cnt,
                                                  float* __restrict__ dinv,
                                                  int* __restrict__ srcs,
                                                  const AT* __restrict__ X,
                                                  const _Float16* __restrict__ WT,
                                                  _Float16* __restrict__ G,
                                                  int n, int nbk, int nbin) {
    __shared__ __align__(16) char smem[128 * WPAD * 2];   // 34816 B union
    int tid = threadIdx.x;

    if ((int)blockIdx.x < nbk) {
        // ---------------- CSR path ----------------
        int* stage = (int*)smem;                    // [SLAB_CAP] 20480 B
        int* lcnt  = (int*)(smem + 20480);          // [256]
        int* lpos  = (int*)(smem + 21504);          // [256]
        int* curs  = (int*)(smem + 22528);          // [1]
        // R24: bijective chunked XCD swizzle (m204 form): blocks with equal
        // blockIdx%8 (same XCD under round-robin) get CONSECUTIVE buckets.
        int b;
        {
            int i = blockIdx.x;
            int q = nbk >> 3, r = nbk & 7;
            int xcd = i & 7, j = i >> 3;
            b = (xcd < r ? xcd * (q + 1) : r * (q + 1) + (xcd - r) * q) + j;
        }
        int prow = nbk + 1;
        if (tid == 0) *curs = 0;
        __syncthreads();
        // phase A: pull my bucket's edges from private segments into LDS
        for (int seg = tid; seg < nbin; seg += 256) {
            const int* pp = P + (size_t)seg * prow + b;
            int p0 = pp[0], p1 = pp[1];
            int len = p1 - p0;
            if (len > 0) {
                int off = atomicAdd(curs, len);
                const int* sp = bins + (size_t)seg * BSC_EDGES + p0;
                for (int i = 0; i < len; ++i) stage[off + i] = sp[i];
            }
        }
        __syncthreads();
        int tot = *curs;
        // phase B: counting sort over 256 dst slots
        lcnt[tid] = 0;
        __syncthreads();
        for (int i = tid; i < tot; i += 256)
            atomicAdd(&lcnt[stage[i] & 255], 1);
        __syncthreads();
        int c = lcnt[tid];
        lpos[tid] = c;
        __syncthreads();
        for (int off = 1; off < 256; off <<= 1) {
            int t = (tid >= off) ? lpos[tid - off] : 0;
            __syncthreads();
            lpos[tid] += t;
            __syncthreads();
        }
        int rs = b * SLAB_CAP + lpos[tid] - c;   // row start in srcs slab
        int v = (b << BK_SHIFT) + tid;
        if (v < n) {
            row_start[v] = rs;
            cnt[v] = c;
            dinv[v] = rsqrtf((float)c + 1.0f);
        }
        __syncthreads();
        lpos[tid] = rs;                 // reuse as fill cursor
        __syncthreads();
        for (int i = tid; i < tot; i += 256) {
            int p = stage[i];
            int loc = atomicAdd(&lpos[p & 255], 1);
            srcs[loc] = p >> 8;
        }
        return;
    }

    // ---------------- GEMM path (unscaled epilogue) ----------------
    _Float16* Wl = (_Float16*)smem;    // [128 * WPAD]
    {
        const half8* w8 = (const half8*)WT;
#pragma unroll
        for (int i = 0; i < 8; ++i) {
            int idx = i * 256 + tid;
            int r = idx >> 4, cc = idx & 15;
            *(half8*)(Wl + r * WPAD + cc * 8) = w8[idx];
        }
    }
    __syncthreads();

    auto loadA = [](const AT* p) -> half8 {
        if constexpr (sizeof(AT) == 4) {
            const float4* f = (const float4*)p;
            float4 f0 = f[0], f1 = f[1];
            half8 a;
            a[0] = (_Float16)f0.x; a[1] = (_Float16)f0.y;
            a[2] = (_Float16)f0.z; a[3] = (_Float16)f0.w;
            a[4] = (_Float16)f1.x; a[5] = (_Float16)f1.y;
            a[6] = (_Float16)f1.z; a[7] = (_Float16)f1.w;
            return a;
        } else {
            return *(const half8*)p;
        }
    };

    int bid = blockIdx.x - nbk;
    int wave = tid >> 6, lane = tid & 63;
    int q = lane >> 4, ln = lane & 15;
    int m0 = bid * 128 + wave * 32;
    int mA0 = m0 + ln;      if (mA0 >= n) mA0 = n - 1;
    int mA1 = m0 + 16 + ln; if (mA1 >= n) mA1 = n - 1;
    const AT* xr0 = X + (size_t)mA0 * 128;
    const AT* xr1 = X + (size_t)mA1 * 128;

    floatx4 acc[2][8];
#pragma unroll
    for (int p = 0; p < 2; ++p)
#pragma unroll
        for (int t = 0; t < 8; ++t) acc[p][t] = (floatx4){0.f, 0.f, 0.f, 0.f};

#pragma unroll
    for (int kc = 0; kc < 128; kc += 32) {
        half8 a0 = loadA(xr0 + kc + q * 8);
        half8 a1 = loadA(xr1 + kc + q * 8);
#pragma unroll
        for (int t = 0; t < 8; ++t) {
            half8 b = *(const half8*)(Wl + (size_t)(t * 16 + ln) * WPAD + kc + q * 8);
            acc[0][t] = __builtin_amdgcn_mfma_f32_16x16x32_f16(a0, b, acc[0][t], 0, 0, 0);
            acc[1][t] = __builtin_amdgcn_mfma_f32_16x16x32_f16(a1, b, acc[1][t], 0, 0, 0);
        }
    }

#pragma unroll
    for (int p = 0; p < 2; ++p) {
#pragma unroll
        for (int r = 0; r < 4; ++r) {
            int row = m0 + p * 16 + q * 4 + r;
            if (row < n) {
                _Float16* grow = G + (size_t)row * 128 + ln;
#pragma unroll
                for (int t = 0; t < 8; ++t)
                    grow[t * 16] = (_Float16)acc[p][t][r];
            }
        }
    }
}

// ---------------------------------------------------------------------------
// Standalone unscaled GEMM (layer 2). (R18-exact)
// ---------------------------------------------------------------------------
template <typename AT>
__global__ __launch_bounds__(256) void k_gemm_mfma(const AT* __restrict__ X,
                                                   const _Float16* __restrict__ WT,
                                                   _Float16* __restrict__ G, int n) {
    __shared__ _Float16 Wl[128 * WPAD];
    int tid = threadIdx.x;
    {
        const half8* w8 = (const half8*)WT;
#pragma unroll
        for (int i = 0; i < 8; ++i) {
            int idx = i * 256 + tid;
            int r = idx >> 4, cc = idx & 15;
            *(half8*)(Wl + r * WPAD + cc * 8) = w8[idx];
        }
    }
    __syncthreads();

    auto loadA = [](const AT* p) -> half8 {
        if constexpr (sizeof(AT) == 4) {
            const float4* f = (const float4*)p;
            float4 f0 = f[0], f1 = f[1];
            half8 a;
            a[0] = (_Float16)f0.x; a[1] = (_Float16)f0.y;
            a[2] = (_Float16)f0.z; a[3] = (_Float16)f0.w;
            a[4] = (_Float16)f1.x; a[5] = (_Float16)f1.y;
            a[6] = (_Float16)f1.z; a[7] = (_Float16)f1.w;
            return a;
        } else {
            return *(const half8*)p;
        }
    };

    int wave = tid >> 6, lane = tid & 63;
    int q = lane >> 4, ln = lane & 15;
    int m0 = blockIdx.x * 128 + wave * 32;
    int mA0 = m0 + ln;      if (mA0 >= n) mA0 = n - 1;
    int mA1 = m0 + 16 + ln; if (mA1 >= n) mA1 = n - 1;
    const AT* xr0 = X + (size_t)mA0 * 128;
    const AT* xr1 = X + (size_t)mA1 * 128;

    floatx4 acc[2][8];
#pragma unroll
    for (int p = 0; p < 2; ++p)
#pragma unroll
        for (int t = 0; t < 8; ++t) acc[p][t] = (floatx4){0.f, 0.f, 0.f, 0.f};

#pragma unroll
    for (int kc = 0; kc < 128; kc += 32) {
        half8 a0 = loadA(xr0 + kc + q * 8);
        half8 a1 = loadA(xr1 + kc + q * 8);
#pragma unroll
        for (int t = 0; t < 8; ++t) {
            half8 b = *(const half8*)(Wl + (size_t)(t * 16 + ln) * WPAD + kc + q * 8);
            acc[0][t] = __builtin_amdgcn_mfma_f32_16x16x32_f16(a0, b, acc[0][t], 0, 0, 0);
            acc[1][t] = __builtin_amdgcn_mfma_f32_16x16x32_f16(a1, b, acc[1][t], 0, 0, 0);
        }
    }

#pragma unroll
    for (int p = 0; p < 2; ++p) {
#pragma unroll
        for (int r = 0; r < 4; ++r) {
            int row = m0 + p * 16 + q * 4 + r;
            if (row < n) {
                _Float16* grow = G + (size_t)row * 128 + ln;
#pragma unroll
                for (int t = 0; t < 8; ++t)
                    grow[t * 16] = (_Float16)acc[p][t][r];
            }
        }
    }
}

// ---------------------------------------------------------------------------
// Gather + bias + relu -> Z (fp16). 16 lanes/node, half8 rows, fp32 accum.
// Per-edge dinv[s] scaling. 4-deep unroll. Full dispatch (R18-exact;
// R23 split reverted: +13.6 us for 4 extra dispatches).
// ---------------------------------------------------------------------------
__global__ __launch_bounds__(256) void k_gather_relu(const _Float16* __restrict__ G,
                                                     const int* __restrict__ srcs,
                                                     const int* __restrict__ row_start,
                                                     const int* __restrict__ cnt,
                                                     const float* __restrict__ dinv,
                                                     const float* __restrict__ bias,
                                                     _Float16* __restrict__ Z, int n) {
    int v = blockIdx.x * 16 + (threadIdx.x >> 4);
    int lane = threadIdx.x & 15;
    if (v >= n) return;
    const half8* G8 = (const half8*)G;

    float dv = dinv[v];
    half8 self = G8[(size_t)v * 16 + lane];
    float acc[8], acc2[8];
#pragma unroll
    for (int j = 0; j < 8; ++j) { acc[j] = dv * (float)self[j]; acc2[j] = 0.f; }

    int beg = row_start[v], deg = cnt[v];
    int e = 0;
    for (; e + 3 < deg; e += 4) {
        int s0 = srcs[beg + e];
        int s1 = srcs[beg + e + 1];
        int s2 = srcs[beg + e + 2];
        int s3 = srcs[beg + e + 3];
        float d0 = dinv[s0];
        float d1 = dinv[s1];
        float d2 = dinv[s2];
        float d3 = dinv[s3];
        half8 t0 = G8[(size_t)s0 * 16 + lane];
        half8 t1 = G8[(size_t)s1 * 16 + lane];
        half8 t2 = G8[(size_t)s2 * 16 + lane];
        half8 t3 = G8[(size_t)s3 * 16 + lane];
#pragma unroll
        for (int j = 0; j < 8; ++j) {
            acc[j]  += d0 * (float)t0[j] + d1 * (float)t1[j];
            acc2[j] += d2 * (float)t2[j] + d3 * (float)t3[j];
        }
    }
    for (; e < deg; ++e) {
        int s0 = srcs[beg + e];
        float d0 = dinv[s0];
        half8 t0 = G8[(size_t)s0 * 16 + lane];
#pragma unroll
        for (int j = 0; j < 8; ++j) acc[j] += d0 * (float)t0[j];
    }

    const float4* b4 = (const float4*)bias;
    float4 bb0 = b4[lane * 2], bb1 = b4[lane * 2 + 1];
    float bf[8] = {bb0.x, bb0.y, bb0.z, bb0.w, bb1.x, bb1.y, bb1.z, bb1.w};
    half8 zo;
#pragma unroll
    for (int j = 0; j < 8; ++j) {
        float z = dv * (acc[j] + acc2[j]) + bf[j];
        zo[j] = (_Float16)fmaxf(z, 0.f);
    }
    ((half8*)Z)[(size_t)v * 16 + lane] = zo;
}

// ---------------------------------------------------------------------------
// Decode: out[e] = dot(Z[s_e], Z[d_e]) over 128 dims (fp16 rows, fp32 accum).
// ---------------------------------------------------------------------------
__global__ __launch_bounds__(256) void k_decode(const _Float16* __restrict__ Z,
                                                const int* __restrict__ eli,
                                                float* __restrict__ out, int el) {
    int sub = threadIdx.x >> 4, lane = threadIdx.x & 15;
    int e = blockIdx.x * 16 + sub;
    if (e >= el) return;
    int s = eli[e], d = eli[el + e];
    const half8* Z8 = (const half8*)Z;
    half8 a = Z8[(size_t)s * 16 + lane];
    half8 b = Z8[(size_t)d * 16 + lane];
    float dot = 0.f;
#pragma unroll
    for (int j = 0; j < 8; ++j) dot += (float)a[j] * (float)b[j];
#pragma unroll
    for (int off = 8; off; off >>= 1) dot += __shfl_down(dot, off, 16);
    if (lane == 0) out[e] = dot;
}

extern "C" void kernel_launch(void* const* d_in, const int* in_sizes, int n_in,
                              void* d_out, int out_size, void* d_ws, size_t ws_size,
                              hipStream_t stream) {
    const float* x  = (const float*)d_in[0];
    const int*  ei  = (const int*)d_in[1];
    const int*  eli = (const int*)d_in[2];
    const float* W1 = (const float*)d_in[3];
    const float* b1 = (const float*)d_in[4];
    const float* W2 = (const float*)d_in[5];
    const float* b2 = (const float*)d_in[6];
    float* out = (float*)d_out;

    const int N  = in_sizes[0] / 128;
    const int E  = in_sizes[1] / 2;
    const int EL = in_sizes[2] / 2;
    const int* src = ei;
    const int* dst = ei + E;
    const int NBK  = (N + 255) >> BK_SHIFT;                 // 391
    const int NBIN = (E + BSC_EDGES - 1) / BSC_EDGES;       // 782
    const int GB   = (N + 127) / 128;                       // 782

    char* ws = (char*)d_ws;
    size_t off = 0;
    auto alloc = [&](size_t bytes) -> void* {
        void* p = ws + off;
        off += bytes;
        off = (off + 255) & ~(size_t)255;
        return p;
    };
    int*       cnt       = (int*)alloc((size_t)N * 4);
    int*       row_start = (int*)alloc((size_t)N * 4);
    float*     dinv      = (float*)alloc((size_t)N * 4);
    _Float16*  WT1       = (_Float16*)alloc(128 * 128 * 2);
    _Float16*  WT2       = (_Float16*)alloc(128 * 128 * 2);
    int*       srcs      = (int*)alloc((size_t)NBK * SLAB_CAP * 4);
    int*       bins      = (int*)alloc((size_t)NBIN * BSC_EDGES * 4);
    int*       P         = (int*)alloc((size_t)NBIN * (NBK + 1) * 4);
    _Float16*  buf0      = (_Float16*)alloc((size_t)N * 128 * 2);  // h1 -> h2
    _Float16*  buf1      = (_Float16*)alloc((size_t)N * 128 * 2);  // z1 -> z2

    // private binning (+ weight prep in tail blocks) — R18-exact
    k_bin<<<NBIN + 256, 256, 0, stream>>>(src, dst, bins, P, E, NBK, NBIN,
                                          W1, W2, WT1, WT2);

    // fused: csr (391 blocks, XCD-swizzled buckets) || gemm1 (782 blocks)
    k_csr_gemm<float><<<NBK + GB, 256, 0, stream>>>(bins, P, row_start, cnt, dinv,
                                                    srcs, x, WT1, buf0, N, NBK, NBIN);

    // z1 = relu(dinv*(dinv*h1[v] + sum dinv[s]*h1[s]) + b1) -> buf1
    k_gather_relu<<<(N + 15) / 16, 256, 0, stream>>>(buf0, srcs, row_start, cnt, dinv, b1, buf1, N);
    // layer 2: h2 = z1@W2 -> buf0 ; z2 -> buf1
    k_gemm_mfma<_Float16><<<GB, 256, 0, stream>>>(buf1, WT2, buf0, N);
    k_gather_relu<<<(N + 15) / 16, 256, 0, stream>>>(buf0, srcs, row_start, cnt, dinv, b2, buf1, N);
    // decode
    k_decode<<<(EL + 15) / 16, 256, 0, stream>>>(buf1, eli, out, EL);
}